// Round 3
// baseline (389.189 us; speedup 1.0000x reference)
//
#include <hip/hip_runtime.h>

#define KMAX 17            // edges per thread in count/scatter
#define CTH  256           // threads per count/scatter block
#define EVB  (KMAX * CTH)  // 4352 events per block

__device__ __forceinline__ unsigned short f2bf(float x) {   // RNE
    unsigned u = __float_as_uint(x);
    u += 0x7FFF + ((u >> 16) & 1);
    return (unsigned short)(u >> 16);
}

// ---------------- count events per (bucket, block) ----------------
__global__ __launch_bounds__(CTH) void k_count(const int* __restrict__ src,
        const int* __restrict__ dst, int* __restrict__ tab,
        int E, int NBK, int NBC) {
    __shared__ int cS[512], cD[512];
    const int t = threadIdx.x;
    for (int i = t; i < 512; i += CTH) { cS[i] = 0; cD[i] = 0; }
    __syncthreads();
    const int e0 = blockIdx.x * EVB;
    int e1 = e0 + EVB; if (e1 > E) e1 = E;
    for (int e = e0 + t; e < e1; e += CTH) {
        atomicAdd(&cS[src[e] >> 8], 1);
        atomicAdd(&cD[dst[e] >> 8], 1);
    }
    __syncthreads();
    const int col = (blockIdx.x & 7) * (NBC >> 3) + (blockIdx.x >> 3);
    for (int b = t; b < NBK; b += CTH) {
        tab[(size_t)b * NBC + col]         = cS[b];
        tab[(size_t)(NBK + b) * NBC + col] = cD[b];
    }
}

// ---------------- hierarchical exclusive scan (3 phases) ----------------
__global__ __launch_bounds__(256) void k_scanA(const int* __restrict__ tab,
                                               int* __restrict__ bsum, int Ntab) {
    __shared__ int red[256];
    const int t = threadIdx.x;
    const int base = blockIdx.x * 2048 + t * 8;
    int s = 0;
#pragma unroll
    for (int k = 0; k < 8; ++k) { int i = base + k; if (i < Ntab) s += tab[i]; }
    red[t] = s; __syncthreads();
    for (int off = 128; off > 0; off >>= 1) {
        if (t < off) red[t] += red[t + off];
        __syncthreads();
    }
    if (t == 0) bsum[blockIdx.x] = red[0];
}

__global__ __launch_bounds__(256) void k_scanB(int* __restrict__ bsum, int NB) {
    __shared__ int sc[256];
    __shared__ int carry;
    const int t = threadIdx.x;
    if (t == 0) carry = 0;
    __syncthreads();
    for (int base = 0; base < NB; base += 256) {
        const int i = base + t;
        const int v = (i < NB) ? bsum[i] : 0;
        sc[t] = v; __syncthreads();
        for (int off = 1; off < 256; off <<= 1) {
            int add = (t >= off) ? sc[t - off] : 0;
            __syncthreads();
            sc[t] += add;
            __syncthreads();
        }
        if (i < NB) bsum[i] = carry + sc[t] - v;   // exclusive
        __syncthreads();
        if (t == 255) carry += sc[255];
        __syncthreads();
    }
}

__global__ __launch_bounds__(256) void k_scanC(int* __restrict__ tab,
                                               const int* __restrict__ bsum, int Ntab) {
    __shared__ int sc[256];
    const int t = threadIdx.x;
    const int base = blockIdx.x * 2048 + t * 8;
    int v[8]; int s = 0;
#pragma unroll
    for (int k = 0; k < 8; ++k) { int i = base + k; v[k] = (i < Ntab) ? tab[i] : 0; s += v[k]; }
    sc[t] = s; __syncthreads();
    for (int off = 1; off < 256; off <<= 1) {
        int add = (t >= off) ? sc[t - off] : 0;
        __syncthreads();
        sc[t] += add;
        __syncthreads();
    }
    int run = bsum[blockIdx.x] + sc[t] - s;
#pragma unroll
    for (int k = 0; k < 8; ++k) {
        int i = base + k;
        if (i < Ntab) { tab[i] = run; run += v[k]; }
    }
    if (base < Ntab && Ntab <= base + 8) tab[Ntab] = run;   // sentinel = 2E
}

// ---------------- scatter: LDS-staged, bucket-ordered dump ----------------
__global__ __launch_bounds__(CTH) void k_scatter(const int* __restrict__ src,
        const int* __restrict__ dst, const int* __restrict__ tab,
        unsigned char* __restrict__ srecs, unsigned* __restrict__ drecs,
        int E, int NBK, int NBC) {
    __shared__ unsigned dstage[EVB];          // 17.4 KB
    __shared__ unsigned char sstage[EVB];     // 4.4 KB
    __shared__ unsigned off[513];             // packed exclusive offsets
    __shared__ unsigned pos[512];             // packed running counters
    __shared__ int bS[512], bD[512];
    __shared__ unsigned red[256];
    const int t = threadIdx.x;
    pos[t] = 0; pos[t + 256] = 0;
    __syncthreads();
    const int e0 = blockIdx.x * EVB;
    const int e1full = e0 + EVB;
    const int e1 = (e1full > E) ? E : e1full;

    int sv[KMAX], dv[KMAX];
#pragma unroll
    for (int k = 0; k < KMAX; ++k) {
        const int e = e0 + k * CTH + t;
        if (e < e1) {
            sv[k] = src[e]; dv[k] = dst[e];
            atomicAdd(&pos[sv[k] >> 8], 1u);
            atomicAdd(&pos[dv[k] >> 8], 0x10000u);
        }
    }
    __syncthreads();
    const unsigned v0 = pos[2 * t], v1 = pos[2 * t + 1];
    const unsigned ps = v0 + v1;
    red[t] = ps;
    __syncthreads();
    for (int o = 1; o < 256; o <<= 1) {
        unsigned add = (t >= o) ? red[t - o] : 0;
        __syncthreads();
        red[t] += add;
        __syncthreads();
    }
    const unsigned base = red[t] - ps;
    off[2 * t] = base;
    off[2 * t + 1] = base + v0;
    if (t == 255) off[512] = red[255];
    __syncthreads();
    pos[t] = off[t]; pos[t + 256] = off[t + 256];
    __syncthreads();
#pragma unroll
    for (int k = 0; k < KMAX; ++k) {
        const int e = e0 + k * CTH + t;
        if (e < e1) {
            const int s = sv[k], d = dv[k];
            const unsigned rs = atomicAdd(&pos[s >> 8], 1u);
            sstage[rs & 0xFFFFu] = (unsigned char)(s & 255);
            const unsigned rd = atomicAdd(&pos[d >> 8], 0x10000u);
            dstage[rd >> 16] = ((unsigned)s << 8) | (unsigned)(d & 255);
        }
    }
    const int col = (blockIdx.x & 7) * (NBC >> 3) + (blockIdx.x >> 3);
    for (int b = t; b < NBK; b += CTH) {
        bS[b] = tab[(size_t)b * NBC + col];
        bD[b] = tab[(size_t)(NBK + b) * NBC + col] - E;
    }
    __syncthreads();
    const int tot = e1 - e0;
    for (int slot = t; slot < tot; slot += CTH) {       // srecs dump
        int lo = 0, hi = NBK;
        while (hi - lo > 1) {
            const int md = (lo + hi) >> 1;
            if ((off[md] & 0xFFFFu) <= (unsigned)slot) lo = md; else hi = md;
        }
        srecs[bS[lo] + slot - (int)(off[lo] & 0xFFFFu)] = sstage[slot];
    }
    for (int slot = t; slot < tot; slot += CTH) {       // drecs dump
        int lo = 0, hi = NBK;
        while (hi - lo > 1) {
            const int md = (lo + hi) >> 1;
            if ((off[md] >> 16) <= (unsigned)slot) lo = md; else hi = md;
        }
        drecs[bD[lo] + slot - (int)(off[lo] >> 16)] = dstage[slot];
    }
}

// ---------------- partial degree counts: 4 sub-blocks per bucket ----------------
__global__ __launch_bounds__(256) void k_degA(const unsigned char* __restrict__ srecs,
        const unsigned* __restrict__ drecs, const int* __restrict__ tab,
        unsigned* __restrict__ pdeg, int NBK, int NBC, int E) {
    __shared__ int oc[256], ic[256];
    const int b = blockIdx.x >> 2, s = blockIdx.x & 3;
    const int t = threadIdx.x;
    oc[t] = 0; ic[t] = 0;
    __syncthreads();
    const int sA0 = tab[(size_t)b * NBC];
    const int sA1 = tab[(size_t)(b + 1) * NBC];
    const int dA0 = tab[(size_t)(NBK + b) * NBC] - E;
    const int dA1 = tab[(size_t)(NBK + b + 1) * NBC] - E;
    const int sl = sA1 - sA0, dl = dA1 - dA0;
    const int s0 = sA0 + (sl * s) / 4, s1 = sA0 + (sl * (s + 1)) / 4;
    const int d0 = dA0 + (dl * s) / 4, d1 = dA0 + (dl * (s + 1)) / 4;
    for (int i = s0 + t; i < s1; i += 256) atomicAdd(&oc[srecs[i]], 1);
    for (int i = d0 + t; i < d1; i += 256) atomicAdd(&ic[drecs[i] & 255], 1);
    __syncthreads();
    pdeg[(size_t)blockIdx.x * 256 + t] = (unsigned)oc[t] | ((unsigned)ic[t] << 16);
}

// ---------------- fold partial degrees -> per-node norms ----------------
__global__ __launch_bounds__(256) void k_norm(const unsigned* __restrict__ pdeg,
        float* __restrict__ ns, float* __restrict__ nd, int N) {
    const int node = blockIdx.x * 256 + threadIdx.x;
    if (node >= N) return;
    const int bk = node >> 8, w = node & 255;
    int od = 0, idg = 0;
#pragma unroll
    for (int s = 0; s < 4; ++s) {
        const unsigned p = pdeg[(size_t)(bk * 4 + s) * 256 + w];
        od  += (int)(p & 0xFFFFu);
        idg += (int)(p >> 16);
    }
    ns[node] = rsqrtf(fmaxf((float)od, 1.f));
    nd[node] = rsqrtf(fmaxf((float)idg, 1.f));
}

// ---------------- projection: contiguous-row wave GEMV ----------------
// v4 theory test: v1/v2/v3 all read X as 16B-per-lane chunks scattered at
// 1KB stride and all pinned at ~60us (~2 TB/s CU ingress) despite 4x
// occupancy variation. The float4-copy ubench (6.3 TB/s) uses lane i ->
// base+16i: ONE contiguous 1KB request per wave-instruction. Here every X
// load is exactly that: one wave-load = one full 1KB row (lane i holds
// cols 4i..4i+3). Consequences: K spans lanes, so W lives in REGISTERS
// (lane i holds W rows 4i..4i+3 = 64 VGPR, loaded once), per row
// 64 FMA -> quad shfl_xor reduce -> wave-private LDS transpose (8KB, no
// barriers anywhere) -> permlane reduce -> packed 32B store. 8-row deep
// static-indexed load pipeline keeps 8 contiguous 1KB requests in flight.
#define GDEPTH 8

__global__ __launch_bounds__(256) void k_gemm(const float* __restrict__ X,
                                              const float* __restrict__ W,
                                              const float* __restrict__ ns,
                                              unsigned short* __restrict__ Hb, int N) {
    __shared__ float scr[4][2][256];   // [wave][slot][quad*16+c], 8 KB
    const int t = threadIdx.x;
    const int wv = t >> 6, lane = t & 63;
    const int R0 = blockIdx.x * 64 + wv * 16;

    // W slice in registers: lane holds W[4*lane+e][4g..4g+3]
    float4 wq[4][4];
#pragma unroll
    for (int e = 0; e < 4; ++e)
#pragma unroll
        for (int g = 0; g < 4; ++g)
            wq[e][g] = *(const float4*)&W[(4 * lane + e) * 16 + 4 * g];

    // ns for the wave's 16 rows staged in lanes 0..15
    float nsv = 0.f;
    {
        const int rr = R0 + (lane & 15);
        if (lane < 16 && rr < N) nsv = ns[rr];
    }

    float4 xbuf[GDEPTH];
#pragma unroll
    for (int j = 0; j < GDEPTH; ++j) {
        const int row = R0 + j;
        xbuf[j] = (row < N) ? *(const float4*)&X[(size_t)row * 256 + 4 * lane]
                            : float4{0.f, 0.f, 0.f, 0.f};
    }

    const int Q = lane >> 2, e4 = lane & 3;
    const int c = lane & 15, p = lane >> 4;

#pragma unroll
    for (int j = 0; j < 16; ++j) {
        const float4 xv = xbuf[j & (GDEPTH - 1)];
        if (j + GDEPTH < 16) {                        // issue row j+GDEPTH
            const int row = R0 + j + GDEPTH;
            xbuf[(j + GDEPTH) & (GDEPTH - 1)] =
                (row < N) ? *(const float4*)&X[(size_t)row * 256 + 4 * lane]
                          : float4{0.f, 0.f, 0.f, 0.f};
        }

        float4 acc[4];
#pragma unroll
        for (int g = 0; g < 4; ++g) acc[g] = float4{0.f, 0.f, 0.f, 0.f};
#pragma unroll
        for (int e = 0; e < 4; ++e) {
            const float xs = (e == 0) ? xv.x : (e == 1) ? xv.y
                           : (e == 2) ? xv.z : xv.w;
#pragma unroll
            for (int g = 0; g < 4; ++g) {
                acc[g].x += xs * wq[e][g].x;
                acc[g].y += xs * wq[e][g].y;
                acc[g].z += xs * wq[e][g].z;
                acc[g].w += xs * wq[e][g].w;
            }
        }

        // quad reduce (xor 1, 2) over the 16 accumulated values
#pragma unroll
        for (int g = 0; g < 4; ++g) {
            acc[g].x += __shfl_xor(acc[g].x, 1); acc[g].x += __shfl_xor(acc[g].x, 2);
            acc[g].y += __shfl_xor(acc[g].y, 1); acc[g].y += __shfl_xor(acc[g].y, 2);
            acc[g].z += __shfl_xor(acc[g].z, 1); acc[g].z += __shfl_xor(acc[g].z, 2);
            acc[g].w += __shfl_xor(acc[g].w, 1); acc[g].w += __shfl_xor(acc[g].w, 2);
        }

        // cross-quad via wave-private LDS transpose (no barrier needed)
        float* sw = &scr[wv][j & 1][0];
        const float4 av = (e4 == 0) ? acc[0] : (e4 == 1) ? acc[1]
                        : (e4 == 2) ? acc[2] : acc[3];
        *(float4*)&sw[Q * 16 + e4 * 4] = av;          // contiguous 1KB b128 write

        float s = sw[(4 * p + 0) * 16 + c] + sw[(4 * p + 1) * 16 + c]
                + sw[(4 * p + 2) * 16 + c] + sw[(4 * p + 3) * 16 + c];
        s += __shfl_xor(s, 16);
        s += __shfl_xor(s, 32);

        const float nsj = __shfl(nsv, j, 64);
        const unsigned o = f2bf(s * nsj);
        const unsigned o1 = __shfl_down(o, 1, 64);
        if (p == 0 && (c & 1) == 0) {
            const int row = R0 + j;
            if (row < N)
                *(unsigned*)&Hb[(size_t)row * 16 + c] = o | (o1 << 16);
        }
    }
}

// ---------------- per-bucket edge accumulation in REGISTERS ----------------
__global__ __launch_bounds__(256) void k_gaccum(const unsigned* __restrict__ drecs,
        const int* __restrict__ tab, const int* __restrict__ seg,
        const float* __restrict__ nd, const unsigned short* __restrict__ Hb,
        float* __restrict__ outagg, int N, int NBK, int NBC, int E, int G) {
    __shared__ float lnd[256];
    __shared__ int   lgi[256];
    __shared__ float lhist[256];
    __shared__ float wred[4 * 48];
    const int b = blockIdx.x >> 1, half = blockIdx.x & 1;
    const int t = threadIdx.x;
    const int node0 = b << 8;
    const int gf = seg[node0];
    lhist[t] = 0.f;
    const int node = node0 + t;
    if (node < N) {
        lnd[t] = nd[node];
        lgi[t] = seg[node] - gf;
    }
    __syncthreads();
    const int dA0 = tab[(size_t)(NBK + b) * NBC] - E;
    const int dA1 = tab[(size_t)(NBK + b + 1) * NBC] - E;
    const int mid = dA0 + ((dA1 - dA0) >> 1);
    const int i0 = half ? mid : dA0;
    const int i1 = half ? dA1 : mid;

    float a0[16], a1[16], a2[16];
#pragma unroll
    for (int j = 0; j < 16; ++j) { a0[j] = 0.f; a1[j] = 0.f; a2[j] = 0.f; }

    for (int i = i0 + t; i < i1; i += 256) {
        const unsigned r = drecs[i];
        const int dlow = r & 255;
        const int s = (int)(r >> 8);
        const float w = lnd[dlow];
        const int gi = lgi[dlow];
        const uint4* hp = (const uint4*)(Hb + (size_t)s * 16);
        const uint4 h0 = hp[0];
        const uint4 h1 = hp[1];
        if (gi < 3) {
            const float w0 = (gi == 0) ? w : 0.f;
            const float w1 = (gi == 1) ? w : 0.f;
            const float w2 = (gi == 2) ? w : 0.f;
#define ACC2(u, j0) { \
            float vlo = __uint_as_float((u) << 16); \
            float vhi = __uint_as_float((u) & 0xFFFF0000u); \
            a0[j0] += vlo * w0; a1[j0] += vlo * w1; a2[j0] += vlo * w2; \
            a0[j0+1] += vhi * w0; a1[j0+1] += vhi * w1; a2[j0+1] += vhi * w2; }
            ACC2(h0.x, 0) ACC2(h0.y, 2) ACC2(h0.z, 4) ACC2(h0.w, 6)
            ACC2(h1.x, 8) ACC2(h1.y, 10) ACC2(h1.z, 12) ACC2(h1.w, 14)
#undef ACC2
        } else {
            const unsigned hw[8] = {h0.x, h0.y, h0.z, h0.w, h1.x, h1.y, h1.z, h1.w};
            if (gi < 16) {
#pragma unroll
                for (int q = 0; q < 8; ++q) {
                    atomicAdd(&lhist[gi * 16 + 2 * q],     __uint_as_float(hw[q] << 16) * w);
                    atomicAdd(&lhist[gi * 16 + 2 * q + 1], __uint_as_float(hw[q] & 0xFFFF0000u) * w);
                }
            } else if (gf + gi < G) {
#pragma unroll
                for (int q = 0; q < 8; ++q) {
                    unsafeAtomicAdd(&outagg[(gf + gi) * 16 + 2 * q],     __uint_as_float(hw[q] << 16) * w);
                    unsafeAtomicAdd(&outagg[(gf + gi) * 16 + 2 * q + 1], __uint_as_float(hw[q] & 0xFFFF0000u) * w);
                }
            }
        }
    }

#pragma unroll
    for (int j = 0; j < 16; ++j) {
#pragma unroll
        for (int off = 32; off > 0; off >>= 1) {
            a0[j] += __shfl_down(a0[j], off, 64);
            a1[j] += __shfl_down(a1[j], off, 64);
            a2[j] += __shfl_down(a2[j], off, 64);
        }
    }
    const int wid = t >> 6, lane = t & 63;
    if (lane == 0) {
#pragma unroll
        for (int j = 0; j < 16; ++j) {
            wred[wid * 48 + j]      = a0[j];
            wred[wid * 48 + 16 + j] = a1[j];
            wred[wid * 48 + 32 + j] = a2[j];
        }
    }
    __syncthreads();
    if (t < 48) {
        const float v = wred[t] + wred[48 + t] + wred[96 + t] + wred[144 + t];
        const int g = gf + t / 16;
        if (v != 0.f && g < G) unsafeAtomicAdd(&outagg[g * 16 + (t & 15)], v);
    } else {
        const float v = lhist[t];
        const int g = gf + t / 16;
        if (v != 0.f && g < G) unsafeAtomicAdd(&outagg[g * 16 + (t & 15)], v);
    }
}

// ---------------- final: gcnt via binary search (seg sorted) ----------------
__global__ void k_final(const float* __restrict__ outagg, const int* __restrict__ seg,
                        const float* __restrict__ bias, float* __restrict__ out,
                        int N, int G) {
    int i = blockIdx.x * 256 + threadIdx.x;
    if (i < G * 16) {
        const int g = i >> 4;
        int lo = 0, hi = N;
        while (lo < hi) { int md = (lo + hi) >> 1; if (seg[md] < g) lo = md + 1; else hi = md; }
        const int a = lo; hi = N;
        while (lo < hi) { int md = (lo + hi) >> 1; if (seg[md] <= g) lo = md + 1; else hi = md; }
        const float cnt = (float)(lo - a);
        out[i] = outagg[i] / fmaxf(cnt, 1.f) + bias[i & 15];
    }
}

extern "C" void kernel_launch(void* const* d_in, const int* in_sizes, int n_in,
                              void* d_out, int out_size, void* d_ws, size_t ws_size,
                              hipStream_t stream) {
    const float* X  = (const float*)d_in[0];
    const float* W  = (const float*)d_in[1];
    const float* bb = (const float*)d_in[2];
    const int* esrc = (const int*)d_in[3];
    const int* edst = (const int*)d_in[4];
    const int* seg  = (const int*)d_in[5];
    const int N = in_sizes[5];                 // 100000
    const int E = in_sizes[3];                 // 3200000
    const int G = out_size / 16;               // 256
    const int NBK = (N + 255) >> 8;            // 391 (<=512 required)
    const int NBC = (((E + EVB - 1) / EVB) + 7) & ~7;   // 736 (x8 for swizzle)
    const int Ntab = 2 * NBK * NBC;            // 575552
    const int NBsc = (Ntab + 2047) / 2048;     // 282 scan blocks

    // ws layout (~20.7 MB; srecs/Hb aliased — srecs dead after k_degA)
    unsigned* drecs = (unsigned*)d_ws;                       // E u32 (12.8 MB)
    int* tab        = (int*)(drecs + (size_t)E);             // Ntab+1 ints (2.3 MB)
    int* bsum       = tab + (Ntab + 1);                      // NBsc (<=1024)
    float* nd       = (float*)(bsum + 1024);                 // N
    float* ns       = nd + N;                                // N
    float* outagg   = ns + N;                                // G*16  <- memset
    unsigned* pdeg  = (unsigned*)(outagg + (size_t)G * 16);  // NBK*4*256 (1.6 MB)
    unsigned char* srecs = (unsigned char*)(pdeg + (size_t)NBK * 4 * 256); // E bytes \ alias
    unsigned short* Hb   = (unsigned short*)srecs;                          // N*16   / region

    hipMemsetAsync(outagg, 0, (size_t)G * 16 * 4, stream);

    k_count  <<<NBC, CTH, 0, stream>>>(esrc, edst, tab, E, NBK, NBC);
    k_scanA  <<<NBsc, 256, 0, stream>>>(tab, bsum, Ntab);
    k_scanB  <<<1, 256, 0, stream>>>(bsum, NBsc);
    k_scanC  <<<NBsc, 256, 0, stream>>>(tab, bsum, Ntab);
    k_scatter<<<NBC, CTH, 0, stream>>>(esrc, edst, tab, srecs, drecs, E, NBK, NBC);
    k_degA   <<<NBK * 4, 256, 0, stream>>>(srecs, drecs, tab, pdeg, NBK, NBC, E);
    k_norm   <<<(N + 255) / 256, 256, 0, stream>>>(pdeg, ns, nd, N);
    k_gemm   <<<(N + 63) / 64, 256, 0, stream>>>(X, W, ns, Hb, N);
    k_gaccum <<<NBK * 2, 256, 0, stream>>>(drecs, tab, seg, nd, Hb, outagg, N, NBK, NBC, E, G);
    k_final  <<<(G * 16 + 255) / 256, 256, 0, stream>>>(outagg, seg, bb, (float*)d_out, N, G);
}

// Round 4
// 308.974 us; speedup vs baseline: 1.2596x; 1.2596x over previous
//
#include <hip/hip_runtime.h>

#define KMAX 17            // edges per thread in count/scatter
#define CTH  256           // threads per count/scatter block
#define EVB  (KMAX * CTH)  // 4352 events per block

typedef __attribute__((ext_vector_type(8))) short short8;
typedef __attribute__((ext_vector_type(4))) float f32x4;

__device__ __forceinline__ unsigned short f2bf(float x) {   // RNE
    unsigned u = __float_as_uint(x);
    u += 0x7FFF + ((u >> 16) & 1);
    return (unsigned short)(u >> 16);
}

__device__ __forceinline__ void gld_lds16(const float* g, float* l) {
    __builtin_amdgcn_global_load_lds(
        (const __attribute__((address_space(1))) unsigned*)g,
        (__attribute__((address_space(3))) unsigned*)l, 16, 0, 0);
}

// ---------------- count events per (bucket, block) ----------------
__global__ __launch_bounds__(CTH) void k_count(const int* __restrict__ src,
        const int* __restrict__ dst, int* __restrict__ tab,
        int E, int NBK, int NBC) {
    __shared__ int cS[512], cD[512];
    const int t = threadIdx.x;
    for (int i = t; i < 512; i += CTH) { cS[i] = 0; cD[i] = 0; }
    __syncthreads();
    const int e0 = blockIdx.x * EVB;
    int e1 = e0 + EVB; if (e1 > E) e1 = E;
    for (int e = e0 + t; e < e1; e += CTH) {
        atomicAdd(&cS[src[e] >> 8], 1);
        atomicAdd(&cD[dst[e] >> 8], 1);
    }
    __syncthreads();
    const int col = (blockIdx.x & 7) * (NBC >> 3) + (blockIdx.x >> 3);
    for (int b = t; b < NBK; b += CTH) {
        tab[(size_t)b * NBC + col]         = cS[b];
        tab[(size_t)(NBK + b) * NBC + col] = cD[b];
    }
}

// ---------------- hierarchical exclusive scan (3 phases) ----------------
__global__ __launch_bounds__(256) void k_scanA(const int* __restrict__ tab,
                                               int* __restrict__ bsum, int Ntab) {
    __shared__ int red[256];
    const int t = threadIdx.x;
    const int base = blockIdx.x * 2048 + t * 8;
    int s = 0;
#pragma unroll
    for (int k = 0; k < 8; ++k) { int i = base + k; if (i < Ntab) s += tab[i]; }
    red[t] = s; __syncthreads();
    for (int off = 128; off > 0; off >>= 1) {
        if (t < off) red[t] += red[t + off];
        __syncthreads();
    }
    if (t == 0) bsum[blockIdx.x] = red[0];
}

__global__ __launch_bounds__(256) void k_scanB(int* __restrict__ bsum, int NB) {
    __shared__ int sc[256];
    __shared__ int carry;
    const int t = threadIdx.x;
    if (t == 0) carry = 0;
    __syncthreads();
    for (int base = 0; base < NB; base += 256) {
        const int i = base + t;
        const int v = (i < NB) ? bsum[i] : 0;
        sc[t] = v; __syncthreads();
        for (int off = 1; off < 256; off <<= 1) {
            int add = (t >= off) ? sc[t - off] : 0;
            __syncthreads();
            sc[t] += add;
            __syncthreads();
        }
        if (i < NB) bsum[i] = carry + sc[t] - v;   // exclusive
        __syncthreads();
        if (t == 255) carry += sc[255];
        __syncthreads();
    }
}

__global__ __launch_bounds__(256) void k_scanC(int* __restrict__ tab,
                                               const int* __restrict__ bsum, int Ntab) {
    __shared__ int sc[256];
    const int t = threadIdx.x;
    const int base = blockIdx.x * 2048 + t * 8;
    int v[8]; int s = 0;
#pragma unroll
    for (int k = 0; k < 8; ++k) { int i = base + k; v[k] = (i < Ntab) ? tab[i] : 0; s += v[k]; }
    sc[t] = s; __syncthreads();
    for (int off = 1; off < 256; off <<= 1) {
        int add = (t >= off) ? sc[t - off] : 0;
        __syncthreads();
        sc[t] += add;
        __syncthreads();
    }
    int run = bsum[blockIdx.x] + sc[t] - s;
#pragma unroll
    for (int k = 0; k < 8; ++k) {
        int i = base + k;
        if (i < Ntab) { tab[i] = run; run += v[k]; }
    }
    if (base < Ntab && Ntab <= base + 8) tab[Ntab] = run;   // sentinel = 2E
}

// ---------------- scatter: LDS-staged, bucket-ordered dump ----------------
__global__ __launch_bounds__(CTH) void k_scatter(const int* __restrict__ src,
        const int* __restrict__ dst, const int* __restrict__ tab,
        unsigned char* __restrict__ srecs, unsigned* __restrict__ drecs,
        int E, int NBK, int NBC) {
    __shared__ unsigned dstage[EVB];          // 17.4 KB
    __shared__ unsigned char sstage[EVB];     // 4.4 KB
    __shared__ unsigned off[513];             // packed exclusive offsets
    __shared__ unsigned pos[512];             // packed running counters
    __shared__ int bS[512], bD[512];
    __shared__ unsigned red[256];
    const int t = threadIdx.x;
    pos[t] = 0; pos[t + 256] = 0;
    __syncthreads();
    const int e0 = blockIdx.x * EVB;
    const int e1full = e0 + EVB;
    const int e1 = (e1full > E) ? E : e1full;

    int sv[KMAX], dv[KMAX];
#pragma unroll
    for (int k = 0; k < KMAX; ++k) {
        const int e = e0 + k * CTH + t;
        if (e < e1) {
            sv[k] = src[e]; dv[k] = dst[e];
            atomicAdd(&pos[sv[k] >> 8], 1u);
            atomicAdd(&pos[dv[k] >> 8], 0x10000u);
        }
    }
    __syncthreads();
    const unsigned v0 = pos[2 * t], v1 = pos[2 * t + 1];
    const unsigned ps = v0 + v1;
    red[t] = ps;
    __syncthreads();
    for (int o = 1; o < 256; o <<= 1) {
        unsigned add = (t >= o) ? red[t - o] : 0;
        __syncthreads();
        red[t] += add;
        __syncthreads();
    }
    const unsigned base = red[t] - ps;
    off[2 * t] = base;
    off[2 * t + 1] = base + v0;
    if (t == 255) off[512] = red[255];
    __syncthreads();
    pos[t] = off[t]; pos[t + 256] = off[t + 256];
    __syncthreads();
#pragma unroll
    for (int k = 0; k < KMAX; ++k) {
        const int e = e0 + k * CTH + t;
        if (e < e1) {
            const int s = sv[k], d = dv[k];
            const unsigned rs = atomicAdd(&pos[s >> 8], 1u);
            sstage[rs & 0xFFFFu] = (unsigned char)(s & 255);
            const unsigned rd = atomicAdd(&pos[d >> 8], 0x10000u);
            dstage[rd >> 16] = ((unsigned)s << 8) | (unsigned)(d & 255);
        }
    }
    const int col = (blockIdx.x & 7) * (NBC >> 3) + (blockIdx.x >> 3);
    for (int b = t; b < NBK; b += CTH) {
        bS[b] = tab[(size_t)b * NBC + col];
        bD[b] = tab[(size_t)(NBK + b) * NBC + col] - E;
    }
    __syncthreads();
    const int tot = e1 - e0;
    for (int slot = t; slot < tot; slot += CTH) {       // srecs dump
        int lo = 0, hi = NBK;
        while (hi - lo > 1) {
            const int md = (lo + hi) >> 1;
            if ((off[md] & 0xFFFFu) <= (unsigned)slot) lo = md; else hi = md;
        }
        srecs[bS[lo] + slot - (int)(off[lo] & 0xFFFFu)] = sstage[slot];
    }
    for (int slot = t; slot < tot; slot += CTH) {       // drecs dump
        int lo = 0, hi = NBK;
        while (hi - lo > 1) {
            const int md = (lo + hi) >> 1;
            if ((off[md] >> 16) <= (unsigned)slot) lo = md; else hi = md;
        }
        drecs[bD[lo] + slot - (int)(off[lo] >> 16)] = dstage[slot];
    }
}

// ---------------- partial degree counts: 4 sub-blocks per bucket ----------------
__global__ __launch_bounds__(256) void k_degA(const unsigned char* __restrict__ srecs,
        const unsigned* __restrict__ drecs, const int* __restrict__ tab,
        unsigned* __restrict__ pdeg, int NBK, int NBC, int E) {
    __shared__ int oc[256], ic[256];
    const int b = blockIdx.x >> 2, s = blockIdx.x & 3;
    const int t = threadIdx.x;
    oc[t] = 0; ic[t] = 0;
    __syncthreads();
    const int sA0 = tab[(size_t)b * NBC];
    const int sA1 = tab[(size_t)(b + 1) * NBC];
    const int dA0 = tab[(size_t)(NBK + b) * NBC] - E;
    const int dA1 = tab[(size_t)(NBK + b + 1) * NBC] - E;
    const int sl = sA1 - sA0, dl = dA1 - dA0;
    const int s0 = sA0 + (sl * s) / 4, s1 = sA0 + (sl * (s + 1)) / 4;
    const int d0 = dA0 + (dl * s) / 4, d1 = dA0 + (dl * (s + 1)) / 4;
    for (int i = s0 + t; i < s1; i += 256) atomicAdd(&oc[srecs[i]], 1);
    for (int i = d0 + t; i < d1; i += 256) atomicAdd(&ic[drecs[i] & 255], 1);
    __syncthreads();
    pdeg[(size_t)blockIdx.x * 256 + t] = (unsigned)oc[t] | ((unsigned)ic[t] << 16);
}

// ---------------- fold partial degrees -> per-node norms ----------------
__global__ __launch_bounds__(256) void k_norm(const unsigned* __restrict__ pdeg,
        float* __restrict__ ns, float* __restrict__ nd, int N) {
    const int node = blockIdx.x * 256 + threadIdx.x;
    if (node >= N) return;
    const int bk = node >> 8, w = node & 255;
    int od = 0, idg = 0;
#pragma unroll
    for (int s = 0; s < 4; ++s) {
        const unsigned p = pdeg[(size_t)(bk * 4 + s) * 256 + w];
        od  += (int)(p & 0xFFFFu);
        idg += (int)(p >> 16);
    }
    ns[node] = rsqrtf(fmaxf((float)od, 1.f));
    nd[node] = rsqrtf(fmaxf((float)idg, 1.f));
}

// ---------------- projection via MFMA (2-term bf16 split) ----------------
// v5: X@W on the matrix pipe. W = Wh+Wl, X = Xh+Xl (bf16 truncate + bf16(RNE)
// remainder); XhWh + XhWl + XlWh gives fp32-grade accuracy (dropped XlWl
// <= 2^-16 rel). W fragments live in 64 VGPR per lane, loaded ONCE -> zero
// LDS broadcast traffic (v1/v2's 1.6 GB LDS wall eliminated). X is staged
// wave-privately via global_load_lds: one instruction = one contiguous 1KB
// row, no barriers, next 16-row tile prefetched under MFMA+epilogue.
// k-slot mapping of A/B frags is self-consistent (same permutation on both
// operands => result exact for ANY hw k order); C/D layout is the
// HW-verified col=lane&15, row=(lane>>4)*4+reg.
// LDS ds_read swizzle: row-XOR (r&7)<<4 applied to the gld_lds GLOBAL source
// (write side) and to the ds_read offset (read side) - same involution,
// kills the 16-way conflict of the 1KB-strided b128 reads.
__global__ __launch_bounds__(256) void k_gemm(const float* __restrict__ X,
        const float* __restrict__ W, const float* __restrict__ ns,
        unsigned short* __restrict__ Hb, int N, int NT) {
    __shared__ float lx[4][16][256];           // 64 KB, 16 KB per wave
    const int t = threadIdx.x;
    const int wv = t >> 6, l = t & 63;
    const int c = l & 15, g = l >> 4;
    float* myx = &lx[wv][0][0];

    // ---- W fragments, once per wave: slot (kc,g,j) = W[kc*32+g*8+j][c] ----
    short8 wh[8], wl[8];
#pragma unroll
    for (int kc = 0; kc < 8; ++kc) {
#pragma unroll
        for (int j = 0; j < 8; ++j) {
            const float w = W[(kc * 32 + g * 8 + j) * 16 + c];
            const unsigned u = __float_as_uint(w);
            const unsigned short h = (unsigned short)(u >> 16);     // truncate
            const float hf = __uint_as_float((unsigned)h << 16);
            wh[kc][j] = (short)h;
            wl[kc][j] = (short)f2bf(w - hf);
        }
    }

    const int wgid = blockIdx.x * 4 + wv;
    const int wstr = gridDim.x * 4;

    int tile = wgid;
    if (tile < NT) {                           // prologue stage
        const int r0 = tile * 16;
#pragma unroll
        for (int r = 0; r < 16; ++r) {
            const int row = r0 + r;
            if (row < N)
                gld_lds16((const float*)((const char*)&X[(size_t)row * 256]
                           + ((l * 16) ^ ((r & 7) << 4))), &myx[r * 256]);
        }
    }

    for (; tile < NT; tile += wstr) {
        asm volatile("s_waitcnt vmcnt(0)" ::: "memory");
        __builtin_amdgcn_sched_barrier(0);

        const int sig = (c & 7) << 4;          // this lane's A-row swizzle
        const char* base = (const char*)&myx[c * 256];
        f32x4 acc = {0.f, 0.f, 0.f, 0.f};
#pragma unroll
        for (int kc = 0; kc < 8; ++kc) {
            const float4 xa = *(const float4*)(base + kc * 128 + ((g * 32) ^ sig));
            const float4 xb = *(const float4*)(base + kc * 128 + ((g * 32 + 16) ^ sig));
            const float xs[8] = {xa.x, xa.y, xa.z, xa.w, xb.x, xb.y, xb.z, xb.w};
            short8 ah, al;
#pragma unroll
            for (int j = 0; j < 8; ++j) {
                const unsigned u = __float_as_uint(xs[j]);
                const unsigned short h = (unsigned short)(u >> 16);
                const float hf = __uint_as_float((unsigned)h << 16);
                ah[j] = (short)h;
                al[j] = (short)f2bf(xs[j] - hf);
            }
            acc = __builtin_amdgcn_mfma_f32_16x16x32_bf16(ah, wh[kc], acc, 0, 0, 0);
            acc = __builtin_amdgcn_mfma_f32_16x16x32_bf16(ah, wl[kc], acc, 0, 0, 0);
            acc = __builtin_amdgcn_mfma_f32_16x16x32_bf16(al, wh[kc], acc, 0, 0, 0);
        }

        const int nt2 = tile + wstr;           // prefetch next tile under epilogue
        if (nt2 < NT) {
            const int r0 = nt2 * 16;
#pragma unroll
            for (int r = 0; r < 16; ++r) {
                const int row = r0 + r;
                if (row < N)
                    gld_lds16((const float*)((const char*)&X[(size_t)row * 256]
                               + ((l * 16) ^ ((r & 7) << 4))), &myx[r * 256]);
            }
        }

        // epilogue: C/D row = g*4 + v, col = c  (m89-verified layout)
        const int rowb = tile * 16 + g * 4;
#pragma unroll
        for (int v = 0; v < 4; ++v) {
            const int row = rowb + v;
            if (row < N)
                Hb[(size_t)row * 16 + c] = f2bf(acc[v] * ns[row]);
        }
    }
}

// ---------------- per-bucket edge accumulation in REGISTERS ----------------
__global__ __launch_bounds__(256) void k_gaccum(const unsigned* __restrict__ drecs,
        const int* __restrict__ tab, const int* __restrict__ seg,
        const float* __restrict__ nd, const unsigned short* __restrict__ Hb,
        float* __restrict__ outagg, int N, int NBK, int NBC, int E, int G) {
    __shared__ float lnd[256];
    __shared__ int   lgi[256];
    __shared__ float lhist[256];
    __shared__ float wred[4 * 48];
    const int b = blockIdx.x >> 1, half = blockIdx.x & 1;
    const int t = threadIdx.x;
    const int node0 = b << 8;
    const int gf = seg[node0];
    lhist[t] = 0.f;
    const int node = node0 + t;
    if (node < N) {
        lnd[t] = nd[node];
        lgi[t] = seg[node] - gf;
    }
    __syncthreads();
    const int dA0 = tab[(size_t)(NBK + b) * NBC] - E;
    const int dA1 = tab[(size_t)(NBK + b + 1) * NBC] - E;
    const int mid = dA0 + ((dA1 - dA0) >> 1);
    const int i0 = half ? mid : dA0;
    const int i1 = half ? dA1 : mid;

    float a0[16], a1[16], a2[16];
#pragma unroll
    for (int j = 0; j < 16; ++j) { a0[j] = 0.f; a1[j] = 0.f; a2[j] = 0.f; }

    for (int i = i0 + t; i < i1; i += 256) {
        const unsigned r = drecs[i];
        const int dlow = r & 255;
        const int s = (int)(r >> 8);
        const float w = lnd[dlow];
        const int gi = lgi[dlow];
        const uint4* hp = (const uint4*)(Hb + (size_t)s * 16);
        const uint4 h0 = hp[0];
        const uint4 h1 = hp[1];
        if (gi < 3) {
            const float w0 = (gi == 0) ? w : 0.f;
            const float w1 = (gi == 1) ? w : 0.f;
            const float w2 = (gi == 2) ? w : 0.f;
#define ACC2(u, j0) { \
            float vlo = __uint_as_float((u) << 16); \
            float vhi = __uint_as_float((u) & 0xFFFF0000u); \
            a0[j0] += vlo * w0; a1[j0] += vlo * w1; a2[j0] += vlo * w2; \
            a0[j0+1] += vhi * w0; a1[j0+1] += vhi * w1; a2[j0+1] += vhi * w2; }
            ACC2(h0.x, 0) ACC2(h0.y, 2) ACC2(h0.z, 4) ACC2(h0.w, 6)
            ACC2(h1.x, 8) ACC2(h1.y, 10) ACC2(h1.z, 12) ACC2(h1.w, 14)
#undef ACC2
        } else {
            const unsigned hw[8] = {h0.x, h0.y, h0.z, h0.w, h1.x, h1.y, h1.z, h1.w};
            if (gi < 16) {
#pragma unroll
                for (int q = 0; q < 8; ++q) {
                    atomicAdd(&lhist[gi * 16 + 2 * q],     __uint_as_float(hw[q] << 16) * w);
                    atomicAdd(&lhist[gi * 16 + 2 * q + 1], __uint_as_float(hw[q] & 0xFFFF0000u) * w);
                }
            } else if (gf + gi < G) {
#pragma unroll
                for (int q = 0; q < 8; ++q) {
                    unsafeAtomicAdd(&outagg[(gf + gi) * 16 + 2 * q],     __uint_as_float(hw[q] << 16) * w);
                    unsafeAtomicAdd(&outagg[(gf + gi) * 16 + 2 * q + 1], __uint_as_float(hw[q] & 0xFFFF0000u) * w);
                }
            }
        }
    }

#pragma unroll
    for (int j = 0; j < 16; ++j) {
#pragma unroll
        for (int off = 32; off > 0; off >>= 1) {
            a0[j] += __shfl_down(a0[j], off, 64);
            a1[j] += __shfl_down(a1[j], off, 64);
            a2[j] += __shfl_down(a2[j], off, 64);
        }
    }
    const int wid = t >> 6, lane = t & 63;
    if (lane == 0) {
#pragma unroll
        for (int j = 0; j < 16; ++j) {
            wred[wid * 48 + j]      = a0[j];
            wred[wid * 48 + 16 + j] = a1[j];
            wred[wid * 48 + 32 + j] = a2[j];
        }
    }
    __syncthreads();
    if (t < 48) {
        const float v = wred[t] + wred[48 + t] + wred[96 + t] + wred[144 + t];
        const int g = gf + t / 16;
        if (v != 0.f && g < G) unsafeAtomicAdd(&outagg[g * 16 + (t & 15)], v);
    } else {
        const float v = lhist[t];
        const int g = gf + t / 16;
        if (v != 0.f && g < G) unsafeAtomicAdd(&outagg[g * 16 + (t & 15)], v);
    }
}

// ---------------- final: gcnt via binary search (seg sorted) ----------------
__global__ void k_final(const float* __restrict__ outagg, const int* __restrict__ seg,
                        const float* __restrict__ bias, float* __restrict__ out,
                        int N, int G) {
    int i = blockIdx.x * 256 + threadIdx.x;
    if (i < G * 16) {
        const int g = i >> 4;
        int lo = 0, hi = N;
        while (lo < hi) { int md = (lo + hi) >> 1; if (seg[md] < g) lo = md + 1; else hi = md; }
        const int a = lo; hi = N;
        while (lo < hi) { int md = (lo + hi) >> 1; if (seg[md] <= g) lo = md + 1; else hi = md; }
        const float cnt = (float)(lo - a);
        out[i] = outagg[i] / fmaxf(cnt, 1.f) + bias[i & 15];
    }
}

extern "C" void kernel_launch(void* const* d_in, const int* in_sizes, int n_in,
                              void* d_out, int out_size, void* d_ws, size_t ws_size,
                              hipStream_t stream) {
    const float* X  = (const float*)d_in[0];
    const float* W  = (const float*)d_in[1];
    const float* bb = (const float*)d_in[2];
    const int* esrc = (const int*)d_in[3];
    const int* edst = (const int*)d_in[4];
    const int* seg  = (const int*)d_in[5];
    const int N = in_sizes[5];                 // 100000
    const int E = in_sizes[3];                 // 3200000
    const int G = out_size / 16;               // 256
    const int NBK = (N + 255) >> 8;            // 391 (<=512 required)
    const int NBC = (((E + EVB - 1) / EVB) + 7) & ~7;   // 736 (x8 for swizzle)
    const int Ntab = 2 * NBK * NBC;            // 575552
    const int NBsc = (Ntab + 2047) / 2048;     // 282 scan blocks
    const int NT = (N + 15) / 16;              // 6250 MFMA row-tiles

    // ws layout (~20.7 MB; srecs/Hb aliased — srecs dead after k_degA)
    unsigned* drecs = (unsigned*)d_ws;                       // E u32 (12.8 MB)
    int* tab        = (int*)(drecs + (size_t)E);             // Ntab+1 ints (2.3 MB)
    int* bsum       = tab + (Ntab + 1);                      // NBsc (<=1024)
    float* nd       = (float*)(bsum + 1024);                 // N
    float* ns       = nd + N;                                // N
    float* outagg   = ns + N;                                // G*16  <- memset
    unsigned* pdeg  = (unsigned*)(outagg + (size_t)G * 16);  // NBK*4*256 (1.6 MB)
    unsigned char* srecs = (unsigned char*)(pdeg + (size_t)NBK * 4 * 256); // E bytes \ alias
    unsigned short* Hb   = (unsigned short*)srecs;                          // N*16   / region

    hipMemsetAsync(outagg, 0, (size_t)G * 16 * 4, stream);

    k_count  <<<NBC, CTH, 0, stream>>>(esrc, edst, tab, E, NBK, NBC);
    k_scanA  <<<NBsc, 256, 0, stream>>>(tab, bsum, Ntab);
    k_scanB  <<<1, 256, 0, stream>>>(bsum, NBsc);
    k_scanC  <<<NBsc, 256, 0, stream>>>(tab, bsum, Ntab);
    k_scatter<<<NBC, CTH, 0, stream>>>(esrc, edst, tab, srecs, drecs, E, NBK, NBC);
    k_degA   <<<NBK * 4, 256, 0, stream>>>(srecs, drecs, tab, pdeg, NBK, NBC, E);
    k_norm   <<<(N + 255) / 256, 256, 0, stream>>>(pdeg, ns, nd, N);
    k_gemm   <<<512, 256, 0, stream>>>(X, W, ns, Hb, N, NT);
    k_gaccum <<<NBK * 2, 256, 0, stream>>>(drecs, tab, seg, nd, Hb, outagg, N, NBK, NBC, E, G);
    k_final  <<<(G * 16 + 255) / 256, 256, 0, stream>>>(outagg, seg, bb, (float*)d_out, N, G);
}